// Round 1
// baseline (221.157 us; speedup 1.0000x reference)
//
#include <hip/hip_runtime.h>
#include <stdint.h>

// DeformableFusionAcrossFocus — round 8: intra-block tile pipeline.
// x:(2,64,16,96,96) f32 | w_off:(6,64,3) | b_off:(6) | w_def:(64,64,3) | b_def:(64) -> out f32
// Grid 768 blocks (exactly 3/CU, all resident, no dispatch rounds), 3 tiles/block.
// Tile j of block p: tn = j*768 + f(p), f = (p&~15)|((p&7)<<1)|((p>>3)&1) so blocks
// p,p+8 (same XCD round-robin) work adjacent w-tiles concurrently -> shared 64B lines.
// Pipeline: while tile j runs conv/interp/GEMM, tile j+1's global loads sit in
// registers (issued at loop top). Barriers are RAW s_barrier + lgkmcnt(0)-only waits
// so the prefetch loads stay in flight across them (no vmcnt drain).
// Epilogue: direct scalar stores from acc (lanes 0-7 contiguous -> 32B chunks, same
// coalescing as the old staged path) — no LDS staging, no epilogue barriers.
// Repack: v_cvt_pk_bf16_f32 (1 instr per bf16 pair, RNE) + float2 lerp (pk_fma-able).

typedef __attribute__((ext_vector_type(8))) short short8;
typedef __attribute__((ext_vector_type(4))) float f32x4;
typedef __attribute__((ext_vector_type(2))) float f32x2;
typedef __attribute__((ext_vector_type(4))) unsigned int u32x4;

// LDS (bytes), no overlays, no cross-region hazards:
//  [0,18432)      xs_t bf16 [pos][72 shorts] (row stride 144B; 64 c used + 8 pad)
//  [18432,34816)  xstage bf16 [c*128 + n*8 + w]
//  [34816,37888)  offs f32 [6][128] (per-wave-disjoint pos ranges)
#define XT_OFF   0
#define XG_OFF   18432
#define OFFS_OFF 34816
#define LDS_BYTES 37888   // 3 blocks/CU: 3*37888 = 113664 <= 163840

__device__ __forceinline__ short f2bf(float f) {
  union { float f; uint32_t u; } v; v.f = f;
  uint32_t r = (v.u + 0x7FFFu + ((v.u >> 16) & 1u)) >> 16;
  return (short)r;
}
__device__ __forceinline__ float asf(uint32_t u) {
  union { uint32_t u; float f; } v; v.u = u; return v.f;
}
__device__ __forceinline__ uint32_t cvt_pk_bf16(float lo, float hi) {
  uint32_t d;
  asm("v_cvt_pk_bf16_f32 %0, %1, %2" : "=v"(d) : "v"(lo), "v"(hi));
  return d;
}
// lgkmcnt-only barrier: LDS visibility without draining vmcnt (keeps the
// next-tile global prefetch loads in flight across the barrier).
__device__ __forceinline__ void wg_barrier() {
  asm volatile("s_waitcnt lgkmcnt(0)" ::: "memory");
  __builtin_amdgcn_s_barrier();
}

// ---- prep: pre-swizzle w_def (frags [0,1536)) and w_off (frags [1536,1920)) into ws ----
__global__ __launch_bounds__(256) void prep_kernel(
    const float* __restrict__ w_off, const float* __restrict__ w_def, short8* __restrict__ ws)
{
  int gid = blockIdx.x * 256 + threadIdx.x;
  if (gid < 1536) {                      // q = (mt*6+ks)*64 + lane
    int mt = gid / 384, ks = (gid % 384) >> 6, ll = gid & 63;
    int m = mt * 16 + (ll & 15), rgq = ll >> 4;
    short8 v;
    #pragma unroll
    for (int jj = 0; jj < 8; ++jj) {
      int kk = ks * 32 + rgq * 8 + jj;
      int c = kk & 63, k3 = kk >> 6;
      v[jj] = f2bf(w_def[m * 192 + c * 3 + k3]);
    }
    ws[gid] = v;
  } else if (gid < 1920) {               // q = ks*64 + lane (rows 6..15 zero)
    int q = gid - 1536;
    int ks = q >> 6, ll = q & 63;
    int m = ll & 15, rgq = ll >> 4;
    short8 v;
    #pragma unroll
    for (int jj = 0; jj < 8; ++jj) {
      int kk = ks * 32 + rgq * 8 + jj;
      int c = kk & 63, k3 = kk >> 6;
      v[jj] = (m < 6) ? f2bf(w_off[m * 192 + c * 3 + k3]) : (short)0;
    }
    ws[gid] = v;
  }
}

__global__ __launch_bounds__(256, 3) void deform_main(
    const float* __restrict__ x, const float* __restrict__ b_off,
    const float* __restrict__ b_def, const short8* __restrict__ wfr,
    float* __restrict__ out)
{
  extern __shared__ char smem[];
  uint16_t* xst = (uint16_t*)(smem + XG_OFF);
  float* offs   = (float*)(smem + OFFS_OFF);

  const int t = threadIdx.x, wv = t >> 6, l = t & 63, col = l & 15, rg = l >> 4;
  const int p = blockIdx.x;
  const int f = (p & ~15) | ((p & 7) << 1) | ((p >> 3) & 1);

  const float* xb = nullptr; float* ob = nullptr;
  auto set_tile = [&](int jj) {
    int tn = jj * 768 + f;
    int wt = tn % 12, bh = tn / 12;
    int h = bh % 96, b = bh / 96;
    size_t base = (size_t)b * 9437184 + (size_t)h * 96 + (size_t)(wt * 8);
    xb = x + base; ob = out + base;
  };

  float4 v[8];
  auto load8 = [&]() {
    #pragma unroll
    for (int i = 0; i < 8; ++i) {
      int r = (t >> 1) + i * 128, half = t & 1;     // r = c*16+n
      v[i] = *(const float4*)(xb + (size_t)r * 9216 + half * 4);
    }
  };
  auto stage_write = [&]() {
    #pragma unroll
    for (int i = 0; i < 8; ++i) {
      int r = (t >> 1) + i * 128, half = t & 1;
      uint2 pk;
      pk.x = cvt_pk_bf16(v[i].x, v[i].y);
      pk.y = cvt_pk_bf16(v[i].z, v[i].w);
      *(uint2*)(xst + r * 8 + half * 4) = pk;
    }
  };
  auto transpose_ = [&]() {
    #pragma unroll
    for (int i = 0; i < 4; ++i) {
      int item = t + 256 * i;                // 1024 = 128 pos x 8 cgroups
      int pos = item & 127, cg = item >> 7;
      short8 vv;
      #pragma unroll
      for (int jj = 0; jj < 8; ++jj) vv[jj] = (short)xst[(cg * 8 + jj) * 128 + pos];
      *(short8*)(smem + XT_OFF + pos * 144 + cg * 16) = vv;
    }
  };

  // ---- prologue: stage tile 0 ----
  set_tile(0);
  load8();
  stage_write();
  wg_barrier();
  transpose_();
  wg_barrier();

  #pragma unroll
  for (int j = 0; j < 3; ++j) {
    float* ob_cur = ob;
    if (j < 2) {
      set_tile(j + 1);
      load8();                               // prefetch next tile into registers
      __builtin_amdgcn_sched_barrier(0);     // pin the load issue above the compute
    }

    // ---- offsets conv via MFMA; offs produced & consumed by the SAME wave ----
    {
      f32x4 cacc[2] = {{0.f,0.f,0.f,0.f},{0.f,0.f,0.f,0.f}};
      const short8 zero = {0,0,0,0,0,0,0,0};
      #pragma unroll
      for (int ks = 0; ks < 6; ++ks) {
        short8 av = wfr[1536 + ks * 64 + l];
        int k3 = ks >> 1;
        #pragma unroll
        for (int nt2 = 0; nt2 < 2; ++nt2) {
          int pos = (wv * 2 + nt2) * 16 + col;
          int n = pos >> 3, w = pos & 7;
          int row = n + k3 - 1;
          bool valid = (row >= 0) && (row < 16);
          int rcl = min(max(row, 0), 15);
          short8 bv = *(short8*)(smem + XT_OFF + (rcl * 8 + w) * 144 + rg * 16 + (ks & 1) * 64);
          bv = valid ? bv : zero;
          cacc[nt2] = __builtin_amdgcn_mfma_f32_16x16x32_bf16(av, bv, cacc[nt2], 0, 0, 0);
        }
      }
      #pragma unroll
      for (int nt2 = 0; nt2 < 2; ++nt2) {
        int pos = (wv * 2 + nt2) * 16 + col;
        #pragma unroll
        for (int r = 0; r < 4; ++r) {
          int rowo = rg * 4 + r;
          if (rowo < 6) offs[rowo * 128 + pos] = cacc[nt2][r];
        }
      }
    }
    // no barrier: same-wave LDS ordering suffices (offs pos ranges are per-wave)

    // ---- interp params, per-lane in registers ----
    float a0v[3][2], a1v[3][2]; int rb[3][2];
    #pragma unroll
    for (int k = 0; k < 3; ++k) {
      #pragma unroll
      for (int nt2 = 0; nt2 < 2; ++nt2) {
        int pos = (wv * 2 + nt2) * 16 + col;
        int n = pos >> 3, w = pos & 7;
        float oy = offs[(2 * k) * 128 + pos] + b_off[2 * k];
        float ox = offs[(2 * k + 1) * 128 + pos] + b_off[2 * k + 1];
        float px = (float)(n - 1 + k) + ox;
        float x0f = floorf(px);
        float fx = px - x0f;
        int x0 = (int)x0f;
        float wy = fmaxf(0.f, 1.f - fabsf(oy));
        float wt1v = fx * wy;
        float wt0v = wy - wt1v;
        float a0, a1; int r0;
        if (x0 >= 0 && x0 < 15)  { r0 = x0; a0 = wt0v; a1 = wt1v; }
        else if (x0 == 15)       { r0 = 14; a0 = 0.f;  a1 = wt0v; }
        else if (x0 == -1)       { r0 = 0;  a0 = wt1v; a1 = 0.f;  }
        else                     { r0 = 0;  a0 = 0.f;  a1 = 0.f;  }
        a0v[k][nt2] = a0; a1v[k][nt2] = a1;
        rb[k][nt2] = (r0 * 8 + w) * 144;
      }
    }

    // ---- main GEMM: 64 o x 32 pos per wave, K=192; fully unrolled ----
    f32x4 acc[4][2];
    #pragma unroll
    for (int mt = 0; mt < 4; ++mt) {
      float4 bd = *(const float4*)(b_def + mt * 16 + rg * 4);
      #pragma unroll
      for (int nt2 = 0; nt2 < 2; ++nt2) {
        acc[mt][nt2][0] = bd.x; acc[mt][nt2][1] = bd.y;
        acc[mt][nt2][2] = bd.z; acc[mt][nt2][3] = bd.w;
      }
    }
    #pragma unroll
    for (int k3 = 0; k3 < 3; ++k3) {
      #pragma unroll
      for (int ks2 = 0; ks2 < 2; ++ks2) {
        int ks = k3 * 2 + ks2;
        short8 A[4];
        #pragma unroll
        for (int mt = 0; mt < 4; ++mt) A[mt] = wfr[(mt * 6 + ks) * 64 + l];
        #pragma unroll
        for (int nt2 = 0; nt2 < 2; ++nt2) {
          const char* base = smem + XT_OFF + rb[k3][nt2] + rg * 16 + ks2 * 64;
          u32x4 x0 = *(const u32x4*)base;
          u32x4 x1 = *(const u32x4*)(base + 1152);   // tap row r0+1 (8 x stride 144)
          f32x2 A0 = {a0v[k3][nt2], a0v[k3][nt2]};
          f32x2 A1 = {a1v[k3][nt2], a1v[k3][nt2]};
          union { uint32_t w[4]; short8 s; } bu;
          #pragma unroll
          for (int q = 0; q < 4; ++q) {
            uint32_t u0 = x0[q], u1 = x1[q];
            f32x2 X0 = { asf(u0 << 16), asf(u0 & 0xffff0000u) };
            f32x2 X1 = { asf(u1 << 16), asf(u1 & 0xffff0000u) };
            f32x2 R = A0 * X0 + A1 * X1;
            bu.w[q] = cvt_pk_bf16(R.x, R.y);
          }
          short8 bv = bu.s;
          #pragma unroll
          for (int mt = 0; mt < 4; ++mt)
            acc[mt][nt2] = __builtin_amdgcn_mfma_f32_16x16x32_bf16(A[mt], bv, acc[mt][nt2], 0, 0, 0);
        }
      }
    }

    // ---- epilogue: direct scalar stores (lanes 0-7 contiguous -> 32B chunks) ----
    #pragma unroll
    for (int mt = 0; mt < 4; ++mt) {
      #pragma unroll
      for (int nt2 = 0; nt2 < 2; ++nt2) {
        int pos = (wv * 2 + nt2) * 16 + col;
        int n = pos >> 3, w = pos & 7;
        float* o0 = ob_cur + (size_t)((mt * 16 + rg * 4) * 16 + n) * 9216 + w;
        #pragma unroll
        for (int r = 0; r < 4; ++r)
          o0[(size_t)r * 147456] = acc[mt][nt2][r];   // o stride = 16*9216
      }
    }

    // ---- stage tile j+1 (loads already in flight since loop top) ----
    if (j < 2) {
      stage_write();
      wg_barrier();
      transpose_();
      wg_barrier();
    }
  }
}

extern "C" void kernel_launch(void* const* d_in, const int* in_sizes, int n_in,
                              void* d_out, int out_size, void* d_ws, size_t ws_size,
                              hipStream_t stream) {
  (void)in_sizes; (void)n_in; (void)ws_size; (void)out_size;
  const float* x     = (const float*)d_in[0];
  const float* w_off = (const float*)d_in[1];
  const float* b_off = (const float*)d_in[2];
  const float* w_def = (const float*)d_in[3];
  const float* b_def = (const float*)d_in[4];
  float* out = (float*)d_out;
  short8* wfr = (short8*)d_ws;   // 1920 * 16B = 30720 B of scratch

  (void)hipFuncSetAttribute((const void*)deform_main,
                            hipFuncAttributeMaxDynamicSharedMemorySize, LDS_BYTES);
  prep_kernel<<<dim3(8), dim3(256), 0, stream>>>(w_off, w_def, wfr);
  deform_main<<<dim3(768), dim3(256), LDS_BYTES, stream>>>(x, b_off, b_def, wfr, out);
}

// Round 3
// 171.083 us; speedup vs baseline: 1.2927x; 1.2927x over previous
//
#include <hip/hip_runtime.h>
#include <stdint.h>

// DeformableFusionAcrossFocus — round 9 (resubmit; prior bench was an infra failure).
// x:(2,64,16,96,96) f32 | w_off:(6,64,3) | b_off:(6) | w_def:(64,64,3) | b_def:(64) -> out f32
// Tile = (b,h,16w): pos = n*16+w in [0,256). Grid 1152 blocks x 512 thr, 1 tile each.
// Every x-row read and out-row write is ONE aligned 64B line (w stride 1, bases are
// 64B multiples) -> zero dependence on cross-block L2 half-line pairing (the r8
// failure mode), half the L2/TA requests per byte vs the 8-wide 32B-segment scheme.
// Skeleton = r7 (proven): stage->transpose->conv->interp->GEMM, plain __syncthreads.
// 8 waves/block, wave wv owns pos [wv*32, wv*32+32): n in {2wv, 2wv+1}, w = col.
// Per-wave shape identical to r7 (2 nt2 chunks x 4 mt x 6 ks). 2 blocks/CU = 16 waves.
// Epilogue: direct stores from acc — each 16-lane group writes one full 64B line.

typedef __attribute__((ext_vector_type(8))) short short8;
typedef __attribute__((ext_vector_type(4))) float f32x4;
typedef __attribute__((ext_vector_type(2))) float f32x2;
typedef __attribute__((ext_vector_type(4))) unsigned int u32x4;

// LDS (bytes):
//  [0,36864)      xs_t bf16 [pos][72 shorts] (row stride 144B; 64 c used + 8 pad)
//  [36864,69632)  xstage bf16 [c*256 + pos] (dead after transpose)
//  [36864,43008)  offs f32 [6][256] (overlays dead xstage; same-wave produce/consume)
#define XT_OFF   0
#define XG_OFF   36864
#define OFFS_OFF 36864
#define LDS_BYTES 69632   // 2 blocks/CU: 2*69632 = 139264 <= 163840

__device__ __forceinline__ short f2bf(float f) {
  union { float f; uint32_t u; } v; v.f = f;
  uint32_t r = (v.u + 0x7FFFu + ((v.u >> 16) & 1u)) >> 16;
  return (short)r;
}
__device__ __forceinline__ float asf(uint32_t u) {
  union { uint32_t u; float f; } v; v.u = u; return v.f;
}
__device__ __forceinline__ uint32_t cvt_pk_bf16(float lo, float hi) {
  uint32_t d;
  asm("v_cvt_pk_bf16_f32 %0, %1, %2" : "=v"(d) : "v"(lo), "v"(hi));
  return d;
}

// ---- prep: pre-swizzle w_def (frags [0,1536)) and w_off (frags [1536,1920)) into ws ----
__global__ __launch_bounds__(256) void prep_kernel(
    const float* __restrict__ w_off, const float* __restrict__ w_def, short8* __restrict__ ws)
{
  int gid = blockIdx.x * 256 + threadIdx.x;
  if (gid < 1536) {                      // q = (mt*6+ks)*64 + lane
    int mt = gid / 384, ks = (gid % 384) >> 6, ll = gid & 63;
    int m = mt * 16 + (ll & 15), rgq = ll >> 4;
    short8 v;
    #pragma unroll
    for (int jj = 0; jj < 8; ++jj) {
      int kk = ks * 32 + rgq * 8 + jj;
      int c = kk & 63, k3 = kk >> 6;
      v[jj] = f2bf(w_def[m * 192 + c * 3 + k3]);
    }
    ws[gid] = v;
  } else if (gid < 1920) {               // q = ks*64 + lane (rows 6..15 zero)
    int q = gid - 1536;
    int ks = q >> 6, ll = q & 63;
    int m = ll & 15, rgq = ll >> 4;
    short8 v;
    #pragma unroll
    for (int jj = 0; jj < 8; ++jj) {
      int kk = ks * 32 + rgq * 8 + jj;
      int c = kk & 63, k3 = kk >> 6;
      v[jj] = (m < 6) ? f2bf(w_off[m * 192 + c * 3 + k3]) : (short)0;
    }
    ws[gid] = v;
  }
}

__global__ __launch_bounds__(512, 4) void deform_main(
    const float* __restrict__ x, const float* __restrict__ b_off,
    const float* __restrict__ b_def, const short8* __restrict__ wfr,
    float* __restrict__ out)
{
  extern __shared__ char smem[];
  uint16_t* xst = (uint16_t*)(smem + XG_OFF);
  float* offs   = (float*)(smem + OFFS_OFF);

  const int t = threadIdx.x, wv = t >> 6, l = t & 63, col = l & 15, rg = l >> 4;
  const int tn = blockIdx.x;
  const int wt = tn % 6, bh = tn / 6;
  const int h = bh % 96, b = bh / 96, w0 = wt * 16;
  const float* xb = x + (size_t)b * 9437184 + h * 96 + w0;

  // ---- stage x -> bf16 xstage [c][pos]; each row read = one full 64B line ----
  #pragma unroll
  for (int i = 0; i < 8; ++i) {
    int r = (t >> 2) + i * 128, quad = t & 3;       // r = c*16+n, 4 lanes per 64B row
    float4 v = *(const float4*)(xb + (size_t)r * 9216 + quad * 4);
    uint2 pk;
    pk.x = cvt_pk_bf16(v.x, v.y);
    pk.y = cvt_pk_bf16(v.z, v.w);
    *(uint2*)(xst + r * 16 + quad * 4) = pk;        // xstage idx = c*256 + n*16 + quad*4
  }
  __syncthreads();

  // ---- transpose -> xs_t[pos][c] (b128 writes; stride 144B) ----
  #pragma unroll
  for (int i = 0; i < 4; ++i) {
    int item = t + 512 * i;                // 2048 = 256 pos x 8 cgroups
    int pos = item & 255, cg = item >> 8;
    short8 vv;
    #pragma unroll
    for (int jj = 0; jj < 8; ++jj) vv[jj] = (short)xst[(cg * 8 + jj) * 256 + pos];
    *(short8*)(smem + XT_OFF + pos * 144 + cg * 16) = vv;
  }
  __syncthreads();   // xs_t complete; xstage dead (offs overlays it)

  // ---- offsets conv via MFMA; offs produced & consumed by the SAME wave ----
  {
    f32x4 cacc[2] = {{0.f,0.f,0.f,0.f},{0.f,0.f,0.f,0.f}};
    const short8 zero = {0,0,0,0,0,0,0,0};
    #pragma unroll
    for (int ks = 0; ks < 6; ++ks) {
      short8 av = wfr[1536 + ks * 64 + l];
      int k3 = ks >> 1;
      #pragma unroll
      for (int nt2 = 0; nt2 < 2; ++nt2) {
        int n = wv * 2 + nt2;              // pos = n*16 + col
        int row = n + k3 - 1;
        bool valid = (row >= 0) && (row < 16);
        int rcl = min(max(row, 0), 15);
        short8 bv = *(short8*)(smem + XT_OFF + (rcl * 16 + col) * 144 + rg * 16 + (ks & 1) * 64);
        bv = valid ? bv : zero;
        cacc[nt2] = __builtin_amdgcn_mfma_f32_16x16x32_bf16(av, bv, cacc[nt2], 0, 0, 0);
      }
    }
    #pragma unroll
    for (int nt2 = 0; nt2 < 2; ++nt2) {
      int pos = (wv * 2 + nt2) * 16 + col;
      #pragma unroll
      for (int r = 0; r < 4; ++r) {
        int rowo = rg * 4 + r;
        if (rowo < 6) offs[rowo * 256 + pos] = cacc[nt2][r];
      }
    }
  }
  // no barrier: same-wave LDS ordering suffices (offs pos ranges are per-wave)

  // ---- interp params, per-lane in registers (all loop indices constant) ----
  float a0v[3][2], a1v[3][2]; int rb[3][2];
  #pragma unroll
  for (int k = 0; k < 3; ++k) {
    #pragma unroll
    for (int nt2 = 0; nt2 < 2; ++nt2) {
      int n = wv * 2 + nt2;
      int pos = n * 16 + col;
      float oy = offs[(2 * k) * 256 + pos] + b_off[2 * k];
      float ox = offs[(2 * k + 1) * 256 + pos] + b_off[2 * k + 1];
      float px = (float)(n - 1 + k) + ox;
      float x0f = floorf(px);
      float fx = px - x0f;
      int x0 = (int)x0f;
      float wy = fmaxf(0.f, 1.f - fabsf(oy));
      float wt1v = fx * wy;
      float wt0v = wy - wt1v;
      float a0, a1; int r0;
      if (x0 >= 0 && x0 < 15)  { r0 = x0; a0 = wt0v; a1 = wt1v; }
      else if (x0 == 15)       { r0 = 14; a0 = 0.f;  a1 = wt0v; }  // only row 15 (=x0)
      else if (x0 == -1)       { r0 = 0;  a0 = wt1v; a1 = 0.f;  }  // only row 0 (=x1)
      else                     { r0 = 0;  a0 = 0.f;  a1 = 0.f;  }
      a0v[k][nt2] = a0; a1v[k][nt2] = a1;
      rb[k][nt2] = (r0 * 16 + col) * 144;
    }
  }

  // ---- main GEMM: 64 o x 32 pos per wave, K=192; fully unrolled ----
  f32x4 acc[4][2];
  #pragma unroll
  for (int mt = 0; mt < 4; ++mt) {
    float4 bd = *(const float4*)(b_def + mt * 16 + rg * 4);
    #pragma unroll
    for (int nt2 = 0; nt2 < 2; ++nt2) {
      acc[mt][nt2][0] = bd.x; acc[mt][nt2][1] = bd.y;
      acc[mt][nt2][2] = bd.z; acc[mt][nt2][3] = bd.w;
    }
  }
  #pragma unroll
  for (int k3 = 0; k3 < 3; ++k3) {
    #pragma unroll
    for (int ks2 = 0; ks2 < 2; ++ks2) {
      int ks = k3 * 2 + ks2;
      short8 A[4];
      #pragma unroll
      for (int mt = 0; mt < 4; ++mt) A[mt] = wfr[(mt * 6 + ks) * 64 + l];
      #pragma unroll
      for (int nt2 = 0; nt2 < 2; ++nt2) {
        const char* base = smem + XT_OFF + rb[k3][nt2] + rg * 16 + ks2 * 64;
        u32x4 x0 = *(const u32x4*)base;
        u32x4 x1 = *(const u32x4*)(base + 2304);   // tap row r0+1 (16 pos x stride 144)
        f32x2 A0 = {a0v[k3][nt2], a0v[k3][nt2]};
        f32x2 A1 = {a1v[k3][nt2], a1v[k3][nt2]};
        union { uint32_t w[4]; short8 s; } bu;
        #pragma unroll
        for (int q = 0; q < 4; ++q) {
          uint32_t u0 = x0[q], u1 = x1[q];
          f32x2 X0 = { asf(u0 << 16), asf(u0 & 0xffff0000u) };
          f32x2 X1 = { asf(u1 << 16), asf(u1 & 0xffff0000u) };
          f32x2 R = A0 * X0 + A1 * X1;
          bu.w[q] = cvt_pk_bf16(R.x, R.y);
        }
        short8 bv = bu.s;
        #pragma unroll
        for (int mt = 0; mt < 4; ++mt)
          acc[mt][nt2] = __builtin_amdgcn_mfma_f32_16x16x32_bf16(A[mt], bv, acc[mt][nt2], 0, 0, 0);
      }
    }
  }

  // ---- epilogue: direct stores; each 16-lane group writes one full 64B line ----
  float* ob = out + (size_t)b * 9437184 + h * 96 + w0;
  #pragma unroll
  for (int mt = 0; mt < 4; ++mt) {
    #pragma unroll
    for (int nt2 = 0; nt2 < 2; ++nt2) {
      int n = wv * 2 + nt2;
      float* o0 = ob + (size_t)((mt * 16 + rg * 4) * 16 + n) * 9216 + col;
      #pragma unroll
      for (int r = 0; r < 4; ++r)
        o0[(size_t)r * 147456] = acc[mt][nt2][r];   // o stride = 16*9216
    }
  }
}

extern "C" void kernel_launch(void* const* d_in, const int* in_sizes, int n_in,
                              void* d_out, int out_size, void* d_ws, size_t ws_size,
                              hipStream_t stream) {
  (void)in_sizes; (void)n_in; (void)ws_size; (void)out_size;
  const float* x     = (const float*)d_in[0];
  const float* w_off = (const float*)d_in[1];
  const float* b_off = (const float*)d_in[2];
  const float* w_def = (const float*)d_in[3];
  const float* b_def = (const float*)d_in[4];
  float* out = (float*)d_out;
  short8* wfr = (short8*)d_ws;   // 1920 * 16B = 30720 B of scratch

  (void)hipFuncSetAttribute((const void*)deform_main,
                            hipFuncAttributeMaxDynamicSharedMemorySize, LDS_BYTES);
  prep_kernel<<<dim3(8), dim3(256), 0, stream>>>(w_off, w_def, wfr);
  deform_main<<<dim3(1152), dim3(512), LDS_BYTES, stream>>>(x, b_off, b_def, wfr, out);
}